// Round 2
// baseline (435.622 us; speedup 1.0000x reference)
//
#include <hip/hip_runtime.h>

// Welford running mean/variance over batch dim.
// x: (B=256, C=64, H=64, W=64) fp32.  N = C*H*W = 262144 neurons.
// Reference recurrence per sample b (n starts at n0):
//   nn += (x_b != 0)
//   old_m = m; m += (x_b - m) / (n0 + b + 1); s += (x_b - m) * (x_b - old_m)
// Outputs concatenated flat in d_out (float32):
//   [0, B*N)            : x passthrough
//   [B*N, B*N+N)        : m
//   [+N)                : s
//   [+N)                : nn (int counts written as float — exactly representable)
//   [+1)                : n  (= n0 + B, as float)

constexpr int kB = 256;
constexpr int kN = 64 * 64 * 64; // 262144
constexpr int kBlock = 256;

__global__ __launch_bounds__(kBlock) void welford_fused(
    const float* __restrict__ x,
    const float* __restrict__ m_in,
    const float* __restrict__ s_in,
    const int*   __restrict__ nn_in,
    const int*   __restrict__ n0_in,
    float* __restrict__ out)
{
    const int j4 = blockIdx.x * blockDim.x + threadIdx.x; // float4 group index
    const int j  = j4 * 4;
    if (j >= kN) return;

    float* out_x  = out;
    float* out_m  = out + (size_t)kB * kN;
    float* out_s  = out_m + kN;
    float* out_nn = out_s + kN;
    float* out_n  = out_nn + kN;

    float4 m = *(const float4*)(m_in + j);
    float4 s = *(const float4*)(s_in + j);
    int4  nni = *(const int4*)(nn_in + j);
    const int n0 = n0_in[0]; // wave-uniform

    float4 nn = make_float4((float)nni.x, (float)nni.y, (float)nni.z, (float)nni.w);

#pragma unroll 4
    for (int b = 0; b < kB; ++b) {
        const size_t off = (size_t)b * kN + j;
        const float4 v = *(const float4*)(x + off);
        *(float4*)(out_x + off) = v; // fused passthrough: x read exactly once

        const float inv = 1.0f / (float)(n0 + b + 1);

        {   // .x
            nn.x += (v.x != 0.0f) ? 1.0f : 0.0f;
            const float om = m.x;
            m.x = om + (v.x - om) * inv;
            s.x += (v.x - m.x) * (v.x - om);
        }
        {   // .y
            nn.y += (v.y != 0.0f) ? 1.0f : 0.0f;
            const float om = m.y;
            m.y = om + (v.y - om) * inv;
            s.y += (v.y - m.y) * (v.y - om);
        }
        {   // .z
            nn.z += (v.z != 0.0f) ? 1.0f : 0.0f;
            const float om = m.z;
            m.z = om + (v.z - om) * inv;
            s.z += (v.z - m.z) * (v.z - om);
        }
        {   // .w
            nn.w += (v.w != 0.0f) ? 1.0f : 0.0f;
            const float om = m.w;
            m.w = om + (v.w - om) * inv;
            s.w += (v.w - m.w) * (v.w - om);
        }
    }

    *(float4*)(out_m  + j) = m;
    *(float4*)(out_s  + j) = s;
    *(float4*)(out_nn + j) = nn;
    if (j4 == 0) out_n[0] = (float)(n0 + kB);
}

extern "C" void kernel_launch(void* const* d_in, const int* in_sizes, int n_in,
                              void* d_out, int out_size, void* d_ws, size_t ws_size,
                              hipStream_t stream) {
    const float* x     = (const float*)d_in[0];
    const float* m_in  = (const float*)d_in[1];
    const float* s_in  = (const float*)d_in[2];
    const int*   nn_in = (const int*)d_in[3];
    const int*   n0_in = (const int*)d_in[4];
    float* out = (float*)d_out;

    const int threads = kN / 4;            // 65536
    dim3 grid(threads / kBlock), block(kBlock); // 256 blocks
    welford_fused<<<grid, block, 0, stream>>>(x, m_in, s_in, nn_in, n0_in, out);
}